// Round 1
// baseline (1950.504 us; speedup 1.0000x reference)
//
#include <hip/hip_runtime.h>
#include <math.h>

// WindowAttention (Swin-style) on MI355X — round 0: correct fp32 baseline.
// B=2048, N=49, C=256, H=8, hd=32, nW=64.
// Pipeline: [qkv GEMM] -> [fused attention per (b,h)] -> [proj GEMM in-place on d_out].
// Key algebraic simplification: av(p)+av(p_fg)-av(p_bg) == (p+p_fg-p_bg)@v
// so only ONE PV matmul is needed (saves 5 GFLOP).

#define B_TOT   2048
#define NTOK    49
#define CDIM    256
#define NHEAD   8
#define HDIM    32
#define NWIN    64
#define MROWS   (B_TOT * NTOK)   // 100352
#define QKV_N   (3 * CDIM)       // 768

// ---------------------------------------------------------------------------
// GEMM: Y = A @ W^T + bias.  A:(M,256) row-major, W:(N,256) row-major.
// 64x64 tile, 256 threads, 4x4 microtile with rows/cols strided by 16
// (stride-20 LDS padding -> float4 reads land on 2-way bank aliasing = free).
// M=100352 (mult of 64), N in {768,256}, K=256 — no bounds checks needed.
// ---------------------------------------------------------------------------
__global__ __launch_bounds__(256) void gemm_qkv_kernel(
    const float* __restrict__ A,
    const float* __restrict__ W,
    const float* __restrict__ bias,
    float* __restrict__ Y)
{
    const int K = 256, N = QKV_N;
    __shared__ float As[64 * 20];
    __shared__ float Ws[64 * 20];
    const int t  = threadIdx.x;
    const int tx = t & 15, ty = t >> 4;
    const int m0 = blockIdx.y * 64, n0 = blockIdx.x * 64;
    const int lr = t >> 2;          // 0..63: tile row this thread stages
    const int lk = (t & 3) * 4;     // 0,4,8,12: k-offset (float4)
    float acc[4][4] = {};
    const float* Arow = A + (size_t)(m0 + lr) * K + lk;
    const float* Wrow = W + (size_t)(n0 + lr) * K + lk;
    for (int k0 = 0; k0 < K; k0 += 16) {
        float4 av = *(const float4*)(Arow + k0);
        float4 wv = *(const float4*)(Wrow + k0);
        __syncthreads();
        *(float4*)&As[lr * 20 + lk] = av;
        *(float4*)&Ws[lr * 20 + lk] = wv;
        __syncthreads();
        #pragma unroll
        for (int kk = 0; kk < 16; kk += 4) {
            float4 a[4], b[4];
            #pragma unroll
            for (int i = 0; i < 4; i++) a[i] = *(const float4*)&As[(ty + 16 * i) * 20 + kk];
            #pragma unroll
            for (int j = 0; j < 4; j++) b[j] = *(const float4*)&Ws[(tx + 16 * j) * 20 + kk];
            #pragma unroll
            for (int i = 0; i < 4; i++)
                #pragma unroll
                for (int j = 0; j < 4; j++)
                    acc[i][j] += a[i].x * b[j].x + a[i].y * b[j].y
                               + a[i].z * b[j].z + a[i].w * b[j].w;
        }
    }
    #pragma unroll
    for (int i = 0; i < 4; i++) {
        const int m = m0 + ty + 16 * i;
        #pragma unroll
        for (int j = 0; j < 4; j++) {
            const int n = n0 + tx + 16 * j;
            Y[(size_t)m * N + n] = acc[i][j] + bias[n];
        }
    }
}

// ---------------------------------------------------------------------------
// Fused attention: one block (256 thr = 4 waves) per (batch b, head h).
// LDS: q,k,v (49x32, pad 36), S_base and Pc (49 rows, pad 52), bias table slice.
// S_base = q@k^T*scale + relpos_bias[h] + window_mask[b%64]
// Pc = softmax(S) + softmax(S+fg) - softmax(S+bg);  O = Pc @ v.
// ---------------------------------------------------------------------------
__global__ __launch_bounds__(256) void attn_kernel(
    const float* __restrict__ Y,      // (B*49, 768) qkv output
    const float* __restrict__ wmask,  // (64, 49, 49)
    const float* __restrict__ fg,     // (B, 49, 49)
    const float* __restrict__ bg,     // (B, 49, 49)
    const float* __restrict__ table,  // (169, 8)
    float* __restrict__ O)            // (B*49, 256) — this is d_out
{
    const int blk = blockIdx.x;
    const int b = blk >> 3, h = blk & 7;
    __shared__ float sq[NTOK * 36];
    __shared__ float sk[NTOK * 36];
    __shared__ float sv[NTOK * 36];
    __shared__ float sbase[NTOK * 52];
    __shared__ float spc[NTOK * 52];
    __shared__ float stab[169];
    const int t = threadIdx.x;
    const float scale = 0.17677669529663687f;  // hd^-0.5

    // Stage q (pre-scaled), k, v for this (b,h).
    const float* Yb = Y + (size_t)b * NTOK * QKV_N + h * HDIM;
    for (int idx = t; idx < NTOK * HDIM; idx += 256) {
        const int n = idx >> 5, d = idx & 31;
        sq[n * 36 + d] = Yb[n * QKV_N + d] * scale;
        sk[n * 36 + d] = Yb[n * QKV_N + 256 + d];
        sv[n * 36 + d] = Yb[n * QKV_N + 512 + d];
    }
    for (int idx = t; idx < 169; idx += 256) stab[idx] = table[idx * 8 + h];
    __syncthreads();

    // S_base (2401 entries; ~10 per thread).
    const float* wm = wmask + (size_t)(b & 63) * (NTOK * NTOK);
    for (int e = t; e < NTOK * NTOK; e += 256) {
        const int i = e / 49, j = e - i * 49;
        const float4* qp = (const float4*)(sq + i * 36);
        const float4* kp = (const float4*)(sk + j * 36);
        float s = 0.f;
        #pragma unroll
        for (int d = 0; d < 8; d++) {
            float4 a = qp[d], c = kp[d];
            s += a.x * c.x + a.y * c.y + a.z * c.z + a.w * c.w;
        }
        const int qi = i / 7, qj = i - qi * 7;
        const int ki = j / 7, kj = j - ki * 7;
        s += stab[(qi - ki + 6) * 13 + (qj - kj + 6)];
        s += wm[e];
        sbase[i * 52 + j] = s;
    }
    __syncthreads();

    // 3-way softmax + combine. One wave per row, rows strided by 4.
    const int wave = t >> 6, lane = t & 63;
    const float* fgb = fg + (size_t)b * (NTOK * NTOK);
    const float* bgb = bg + (size_t)b * (NTOK * NTOK);
    for (int i = wave; i < NTOK; i += 4) {
        const bool ok = (lane < NTOK);
        const float sb = ok ? sbase[i * 52 + lane] : -1e30f;
        const float fv = ok ? fgb[i * 49 + lane] : 0.f;
        const float bv = ok ? bgb[i * 49 + lane] : 0.f;
        float x[3] = { sb, sb + fv, sb + bv };
        float pc = 0.f;
        #pragma unroll
        for (int v = 0; v < 3; v++) {
            float m = x[v];
            #pragma unroll
            for (int off = 32; off; off >>= 1) m = fmaxf(m, __shfl_xor(m, off));
            const float e = ok ? __expf(x[v] - m) : 0.f;
            float ssum = e;
            #pragma unroll
            for (int off = 32; off; off >>= 1) ssum += __shfl_xor(ssum, off);
            pc += (v == 2 ? -1.f : 1.f) * e / ssum;
        }
        if (ok) spc[i * 52 + lane] = pc;
    }
    __syncthreads();

    // O = Pc @ v  (49x32 outputs, ~6 per thread).
    float* Ob = O + (size_t)b * NTOK * CDIM + h * HDIM;
    for (int idx = t; idx < NTOK * HDIM; idx += 256) {
        const int i = idx >> 5, d = idx & 31;
        float s = 0.f;
        #pragma unroll 7
        for (int j = 0; j < NTOK; j++) s += spc[i * 52 + j] * sv[j * 36 + d];
        Ob[i * CDIM + d] = s;
    }
}

// ---------------------------------------------------------------------------
// Proj GEMM, IN-PLACE on d_out: Y = Y @ W^T + bias, Y:(100352,256), W:(256,256).
// Safe in-place: block bx owns rows [64bx,64bx+64) exclusively; every global
// A-read is consumed into LDS before the post-store barrier, and epilogue
// writes happen only after all threads pass that barrier.
// BN = 256 (full width) so no cross-block read/write overlap exists.
// ---------------------------------------------------------------------------
__global__ __launch_bounds__(256) void proj_inplace_kernel(
    float* __restrict__ Y,
    const float* __restrict__ W,
    const float* __restrict__ bias)
{
    const int K = 256, N = 256;
    __shared__ float As[64 * 20];
    __shared__ float Ws[256 * 20];
    const int t  = threadIdx.x;
    const int tx = t & 15, ty = t >> 4;
    const int m0 = blockIdx.x * 64;
    const int lr = t >> 2, lk = (t & 3) * 4;
    float acc[4][16] = {};
    const float* Arow = Y + (size_t)(m0 + lr) * K + lk;
    for (int k0 = 0; k0 < K; k0 += 16) {
        float4 av = *(const float4*)(Arow + k0);
        float4 wv[4];
        #pragma unroll
        for (int r = 0; r < 4; r++)
            wv[r] = *(const float4*)(W + (size_t)(lr + 64 * r) * K + lk + k0);
        __syncthreads();
        *(float4*)&As[lr * 20 + lk] = av;
        #pragma unroll
        for (int r = 0; r < 4; r++)
            *(float4*)&Ws[(lr + 64 * r) * 20 + lk] = wv[r];
        __syncthreads();
        #pragma unroll
        for (int kk = 0; kk < 16; kk += 4) {
            float4 a[4];
            #pragma unroll
            for (int i = 0; i < 4; i++) a[i] = *(const float4*)&As[(ty + 16 * i) * 20 + kk];
            #pragma unroll
            for (int j = 0; j < 16; j++) {
                float4 bvec = *(const float4*)&Ws[(tx + 16 * j) * 20 + kk];
                #pragma unroll
                for (int i = 0; i < 4; i++)
                    acc[i][j] += a[i].x * bvec.x + a[i].y * bvec.y
                               + a[i].z * bvec.z + a[i].w * bvec.w;
            }
        }
    }
    #pragma unroll
    for (int i = 0; i < 4; i++) {
        const int m = m0 + ty + 16 * i;
        #pragma unroll
        for (int j = 0; j < 16; j++) {
            const int n = tx + 16 * j;
            Y[(size_t)m * N + n] = acc[i][j] + bias[n];
        }
    }
}

extern "C" void kernel_launch(void* const* d_in, const int* in_sizes, int n_in,
                              void* d_out, int out_size, void* d_ws, size_t ws_size,
                              hipStream_t stream) {
    const float* x      = (const float*)d_in[0];
    const float* mask   = (const float*)d_in[1];
    const float* fg     = (const float*)d_in[2];
    const float* bg     = (const float*)d_in[3];
    const float* qkv_w  = (const float*)d_in[4];
    const float* qkv_b  = (const float*)d_in[5];
    const float* proj_w = (const float*)d_in[6];
    const float* proj_b = (const float*)d_in[7];
    const float* table  = (const float*)d_in[8];
    float* out = (float*)d_out;

    // Workspace: qkv_y = (100352, 768) fp32 = 308.3 MB.
    float* qkv_y = (float*)d_ws;

    dim3 blk(256);
    gemm_qkv_kernel<<<dim3(QKV_N / 64, MROWS / 64), blk, 0, stream>>>(x, qkv_w, qkv_b, qkv_y);
    attn_kernel<<<dim3(B_TOT * NHEAD), blk, 0, stream>>>(qkv_y, mask, fg, bg, table, out);
    proj_inplace_kernel<<<dim3(MROWS / 64), blk, 0, stream>>>(out, proj_w, proj_b);
}

// Round 2
// 893.350 us; speedup vs baseline: 2.1834x; 2.1834x over previous
//
#include <hip/hip_runtime.h>
#include <hip/hip_bf16.h>
#include <math.h>

// WindowAttention on MI355X — round 1: bf16 MFMA GEMMs + leaner attention.
// B=2048, N=49, C=256, H=8, hd=32, nW=64.
// Pipeline: cast x/W to bf16 -> qkv GEMM (MFMA, bf16 out) -> fused attention
// (fp32 math, bf16 in/out, 29.7KB LDS -> 5 blocks/CU) -> proj GEMM (MFMA, fp32 out).
// av(p)+av(p_fg)-av(p_bg) == (p+p_fg-p_bg)@v  => single PV matmul.

#define B_TOT   2048
#define NTOK    49
#define CDIM    256
#define NHEAD   8
#define HDIM    32
#define MROWS   (B_TOT * NTOK)   // 100352
#define QKV_N   (3 * CDIM)       // 768

typedef __attribute__((ext_vector_type(8))) short short8;   // 8 bf16 (4 VGPRs)
typedef __attribute__((ext_vector_type(4))) float floatx4;  // MFMA acc

typedef unsigned int u32_g __attribute__((address_space(1)));
typedef unsigned int u32_l __attribute__((address_space(3)));

__device__ __forceinline__ void gld_lds16(const void* g, void* l) {
    // async global->LDS, 16B per lane; LDS dest must be wave-uniform base.
    __builtin_amdgcn_global_load_lds((const u32_g*)g, (u32_l*)l, 16, 0, 0);
}

__device__ __forceinline__ float bf2f(unsigned short u) {
    union { unsigned int i; float f; } x; x.i = ((unsigned int)u) << 16; return x.f;
}

// ---------------------------------------------------------------------------
// cast fp32 -> bf16, 8 elems/thread.
// ---------------------------------------------------------------------------
__global__ __launch_bounds__(256) void cast_kernel(
    const float* __restrict__ in, __hip_bfloat16* __restrict__ out, int n8)
{
    const int i = blockIdx.x * 256 + threadIdx.x;
    if (i >= n8) return;
    const float4* p = (const float4*)in + (size_t)i * 2;
    float4 a = p[0], b = p[1];
    __hip_bfloat16 r[8];
    r[0] = __float2bfloat16(a.x); r[1] = __float2bfloat16(a.y);
    r[2] = __float2bfloat16(a.z); r[3] = __float2bfloat16(a.w);
    r[4] = __float2bfloat16(b.x); r[5] = __float2bfloat16(b.y);
    r[6] = __float2bfloat16(b.z); r[7] = __float2bfloat16(b.w);
    *(uint4*)(out + (size_t)i * 8) = *(const uint4*)r;
}

// ---------------------------------------------------------------------------
// MFMA GEMM: Y(M,NDIM) = A(M,256) @ W(NDIM,256)^T + bias.  A,W bf16 row-major.
// 128x128 tile, 256 thr = 4 waves in 2x2; each wave 64x64 = 4x4 MFMA tiles.
// BK=64, global_load_lds width 16, LDS 8-bf16 k-blocks XOR-swizzled by row&7
// so fragment ds_read_b128 is 2-way-aliased max (free per m136).
// ---------------------------------------------------------------------------
template<int NDIM, bool OUT_BF16>
__global__ __launch_bounds__(256) void gemm_mfma(
    const __hip_bfloat16* __restrict__ A,
    const __hip_bfloat16* __restrict__ W,
    const float* __restrict__ bias,
    void* __restrict__ Yv)
{
    const int K = 256;
    __shared__ short As[128 * 64];
    __shared__ short Bs[128 * 64];
    const int t = threadIdx.x;
    const int lane = t & 63, w = t >> 6;
    const int wr = w >> 1, wc = w & 1;
    const int q = lane >> 4, l15 = lane & 15;
    const int m0 = blockIdx.y * 128, n0 = blockIdx.x * 128;

    // staging map: chunk c = i*256 + t; row = c>>3 (=i*32 + t>>3), slot kb = t&7,
    // global k-block = slot ^ (row&7).
    const int srow = t >> 3, skb = t & 7;
    const int gkb = skb ^ (srow & 7);
    const __hip_bfloat16* Ag = A + (size_t)(m0 + srow) * K + gkb * 8;
    const __hip_bfloat16* Wg = W + (size_t)(n0 + srow) * K + gkb * 8;

    floatx4 acc[4][4] = {};
    const int swz = l15 & 7;  // row&7 of every fragment this lane reads

    for (int k0 = 0; k0 < K; k0 += 64) {
        __syncthreads();
        #pragma unroll
        for (int i = 0; i < 4; i++) {
            gld_lds16(Ag + (size_t)(i * 32) * K + k0, &As[i * 2048 + w * 512]);
            gld_lds16(Wg + (size_t)(i * 32) * K + k0, &Bs[i * 2048 + w * 512]);
        }
        __syncthreads();
        #pragma unroll
        for (int kk = 0; kk < 2; kk++) {
            const int kbs = ((kk << 2) + q) ^ swz;  // swizzled k-block slot
            short8 af[4], bf[4];
            #pragma unroll
            for (int i = 0; i < 4; i++) {
                af[i] = *(const short8*)&As[(wr * 64 + i * 16 + l15) * 64 + kbs * 8];
                bf[i] = *(const short8*)&Bs[(wc * 64 + i * 16 + l15) * 64 + kbs * 8];
            }
            #pragma unroll
            for (int i = 0; i < 4; i++)
                #pragma unroll
                for (int j = 0; j < 4; j++)
                    acc[i][j] = __builtin_amdgcn_mfma_f32_16x16x32_bf16(
                        af[i], bf[j], acc[i][j], 0, 0, 0);
        }
    }

    // epilogue: D[row=q*4+r (M)][col=l15 (N)] per 16x16 tile.
    #pragma unroll
    for (int j = 0; j < 4; j++) {
        const int n = n0 + wc * 64 + j * 16 + l15;
        const float bv = bias[n];
        #pragma unroll
        for (int i = 0; i < 4; i++) {
            #pragma unroll
            for (int r = 0; r < 4; r++) {
                const int m = m0 + wr * 64 + i * 16 + q * 4 + r;
                const float val = acc[i][j][r] + bv;
                if (OUT_BF16)
                    ((__hip_bfloat16*)Yv)[(size_t)m * NDIM + n] = __float2bfloat16(val);
                else
                    ((float*)Yv)[(size_t)m * NDIM + n] = val;
            }
        }
    }
}

// ---------------------------------------------------------------------------
// Fused attention: one block (4 waves) per (b,h). fp32 math in LDS.
// q/k/v stored 49x32 fp32 unpadded with 4-float chunks XOR-swizzled by row&7
// (conflict-free float4 access, no padding). pc overwrites sbase in place.
// LDS = 3*6.1KB + 10.2KB + 0.7KB = 29.7KB -> 5 blocks/CU.
// ---------------------------------------------------------------------------
__global__ __launch_bounds__(256) void attn_kernel(
    const __hip_bfloat16* __restrict__ Y,   // (B*49, 768) bf16
    const float* __restrict__ wmask,        // (64, 49, 49)
    const float* __restrict__ fg,           // (B, 49, 49)
    const float* __restrict__ bg,           // (B, 49, 49)
    const float* __restrict__ table,        // (169, 8)
    __hip_bfloat16* __restrict__ O)         // (B*49, 256) bf16 -> ws
{
    const int blk = blockIdx.x;
    const int b = blk >> 3, h = blk & 7;
    __shared__ float sq[NTOK * 32];
    __shared__ float sk[NTOK * 32];
    __shared__ float sv[NTOK * 32];
    __shared__ float sbase[NTOK * 52];
    __shared__ float stab[169];
    const int t = threadIdx.x;
    const float scale = 0.17677669529663687f;  // hd^-0.5

    // Stage q (pre-scaled), k, v. 196 threads: one 8-bf16 chunk each per tensor.
    const __hip_bfloat16* Yb = Y + (size_t)b * NTOK * QKV_N + h * HDIM;
    if (t < 196) {
        const int n = t >> 2, e8 = t & 3;
        const int swz = n & 7;
        const int c0 = ((e8 * 2) ^ swz) * 4, c1 = ((e8 * 2 + 1) ^ swz) * 4;
        uint4 qv = *(const uint4*)(Yb + (size_t)n * QKV_N + e8 * 8);
        uint4 kv = *(const uint4*)(Yb + (size_t)n * QKV_N + 256 + e8 * 8);
        uint4 vv = *(const uint4*)(Yb + (size_t)n * QKV_N + 512 + e8 * 8);
        const unsigned int* qu = (const unsigned int*)&qv;
        const unsigned int* ku = (const unsigned int*)&kv;
        const unsigned int* vu = (const unsigned int*)&vv;
        float4 a, c;
        a = make_float4(bf2f(qu[0] & 0xffff), bf2f(qu[0] >> 16), bf2f(qu[1] & 0xffff), bf2f(qu[1] >> 16));
        c = make_float4(bf2f(qu[2] & 0xffff), bf2f(qu[2] >> 16), bf2f(qu[3] & 0xffff), bf2f(qu[3] >> 16));
        a.x *= scale; a.y *= scale; a.z *= scale; a.w *= scale;
        c.x *= scale; c.y *= scale; c.z *= scale; c.w *= scale;
        *(float4*)&sq[n * 32 + c0] = a; *(float4*)&sq[n * 32 + c1] = c;
        a = make_float4(bf2f(ku[0] & 0xffff), bf2f(ku[0] >> 16), bf2f(ku[1] & 0xffff), bf2f(ku[1] >> 16));
        c = make_float4(bf2f(ku[2] & 0xffff), bf2f(ku[2] >> 16), bf2f(ku[3] & 0xffff), bf2f(ku[3] >> 16));
        *(float4*)&sk[n * 32 + c0] = a; *(float4*)&sk[n * 32 + c1] = c;
        a = make_float4(bf2f(vu[0] & 0xffff), bf2f(vu[0] >> 16), bf2f(vu[1] & 0xffff), bf2f(vu[1] >> 16));
        c = make_float4(bf2f(vu[2] & 0xffff), bf2f(vu[2] >> 16), bf2f(vu[3] & 0xffff), bf2f(vu[3] >> 16));
        *(float4*)&sv[n * 32 + c0] = a; *(float4*)&sv[n * 32 + c1] = c;
    }
    for (int idx = t; idx < 169; idx += 256) stab[idx] = table[idx * 8 + h];
    __syncthreads();

    // S_base = q@k^T + relpos + window mask
    const float* wm = wmask + (size_t)(b & 63) * (NTOK * NTOK);
    for (int e = t; e < NTOK * NTOK; e += 256) {
        const int i = e / 49, j = e - i * 49;
        const int si = i & 7, sj = j & 7;
        float s = 0.f;
        #pragma unroll
        for (int c = 0; c < 8; c++) {
            float4 a = *(const float4*)&sq[i * 32 + (c ^ si) * 4];
            float4 k = *(const float4*)&sk[j * 32 + (c ^ sj) * 4];
            s += a.x * k.x + a.y * k.y + a.z * k.z + a.w * k.w;
        }
        const int qi = i / 7, qj = i - qi * 7;
        const int ki = j / 7, kj = j - ki * 7;
        s += stab[(qi - ki + 6) * 13 + (qj - kj + 6)];
        s += wm[e];
        sbase[i * 52 + j] = s;
    }
    __syncthreads();

    // 3-way softmax + combine; pc overwrites sbase row in place (one wave/row).
    const int wave = t >> 6, lane = t & 63;
    const float* fgb = fg + (size_t)b * (NTOK * NTOK);
    const float* bgb = bg + (size_t)b * (NTOK * NTOK);
    for (int i = wave; i < NTOK; i += 4) {
        const bool ok = (lane < NTOK);
        const float sb = ok ? sbase[i * 52 + lane] : -1e30f;
        const float fv = ok ? fgb[i * 49 + lane] : 0.f;
        const float bv = ok ? bgb[i * 49 + lane] : 0.f;
        float x[3] = { sb, sb + fv, sb + bv };
        float pc = 0.f;
        #pragma unroll
        for (int v = 0; v < 3; v++) {
            float m = x[v];
            #pragma unroll
            for (int off = 32; off; off >>= 1) m = fmaxf(m, __shfl_xor(m, off));
            const float e = ok ? __expf(x[v] - m) : 0.f;
            float ssum = e;
            #pragma unroll
            for (int off = 32; off; off >>= 1) ssum += __shfl_xor(ssum, off);
            pc += (v == 2 ? -1.f : 1.f) * e / ssum;
        }
        if (ok) sbase[i * 52 + lane] = pc;
    }
    __syncthreads();

    // O = Pc @ v  -> bf16
    __hip_bfloat16* Ob = O + (size_t)b * NTOK * CDIM + h * HDIM;
    for (int idx = t; idx < NTOK * HDIM; idx += 256) {
        const int i = idx >> 5, d = idx & 31;
        const int c = d >> 2, e = d & 3;
        float s = 0.f;
        #pragma unroll 7
        for (int j = 0; j < NTOK; j++)
            s += sbase[i * 52 + j] * sv[j * 32 + ((c ^ (j & 7)) * 4) + e];
        Ob[(size_t)i * CDIM + d] = __float2bfloat16(s);
    }
}

extern "C" void kernel_launch(void* const* d_in, const int* in_sizes, int n_in,
                              void* d_out, int out_size, void* d_ws, size_t ws_size,
                              hipStream_t stream) {
    const float* x      = (const float*)d_in[0];
    const float* mask   = (const float*)d_in[1];
    const float* fg     = (const float*)d_in[2];
    const float* bg     = (const float*)d_in[3];
    const float* qkv_w  = (const float*)d_in[4];
    const float* qkv_b  = (const float*)d_in[5];
    const float* proj_w = (const float*)d_in[6];
    const float* proj_b = (const float*)d_in[7];
    const float* table  = (const float*)d_in[8];
    float* out = (float*)d_out;

    // ws layout (bytes, all 16B-aligned):
    char* ws = (char*)d_ws;
    __hip_bfloat16* xb  = (__hip_bfloat16*)(ws);                    //  51,380,224 B
    __hip_bfloat16* Ybf = (__hip_bfloat16*)(ws + 51380224);         // 154,140,672 B
    __hip_bfloat16* Obf = (__hip_bfloat16*)(ws + 205520896);        //  51,380,224 B
    __hip_bfloat16* qwb = (__hip_bfloat16*)(ws + 256901120);        //     393,216 B
    __hip_bfloat16* pwb = (__hip_bfloat16*)(ws + 257294336);        //     131,072 B

    dim3 blk(256);
    cast_kernel<<<dim3((MROWS * CDIM / 8 + 255) / 256), blk, 0, stream>>>(x, xb, MROWS * CDIM / 8);
    cast_kernel<<<dim3((QKV_N * CDIM / 8 + 255) / 256), blk, 0, stream>>>(qkv_w, qwb, QKV_N * CDIM / 8);
    cast_kernel<<<dim3((CDIM * CDIM / 8 + 255) / 256), blk, 0, stream>>>(proj_w, pwb, CDIM * CDIM / 8);

    gemm_mfma<QKV_N, true><<<dim3(QKV_N / 128, MROWS / 128), blk, 0, stream>>>(xb, qwb, qkv_b, Ybf);
    attn_kernel<<<dim3(B_TOT * NHEAD), blk, 0, stream>>>(Ybf, mask, fg, bg, table, Obf);
    gemm_mfma<CDIM, false><<<dim3(CDIM / 128, MROWS / 128), blk, 0, stream>>>(Obf, pwb, proj_b, out);
}

// Round 3
// 660.158 us; speedup vs baseline: 2.9546x; 1.3532x over previous
//
#include <hip/hip_runtime.h>
#include <hip/hip_bf16.h>
#include <math.h>

// WindowAttention on MI355X — round 2: MFMA attention (QK^T and PV on matrix
// cores), GEMMs unchanged from round 1.
// B=2048, N=49, C=256, H=8, hd=32, nW=64.
// av(p)+av(p_fg)-av(p_bg) == (p+p_fg-p_bg)@v  => single PV matmul.

#define B_TOT   2048
#define NTOK    49
#define CDIM    256
#define NHEAD   8
#define HDIM    32
#define MROWS   (B_TOT * NTOK)   // 100352
#define QKV_N   (3 * CDIM)       // 768

typedef __attribute__((ext_vector_type(8))) short short8;   // 8 bf16 (4 VGPRs)
typedef __attribute__((ext_vector_type(4))) float floatx4;  // MFMA acc

typedef unsigned int u32_g __attribute__((address_space(1)));
typedef unsigned int u32_l __attribute__((address_space(3)));

__device__ __forceinline__ void gld_lds16(const void* g, void* l) {
    __builtin_amdgcn_global_load_lds((const u32_g*)g, (u32_l*)l, 16, 0, 0);
}

// ---------------------------------------------------------------------------
// cast fp32 -> bf16, 8 elems/thread.
// ---------------------------------------------------------------------------
__global__ __launch_bounds__(256) void cast_kernel(
    const float* __restrict__ in, __hip_bfloat16* __restrict__ out, int n8)
{
    const int i = blockIdx.x * 256 + threadIdx.x;
    if (i >= n8) return;
    const float4* p = (const float4*)in + (size_t)i * 2;
    float4 a = p[0], b = p[1];
    __hip_bfloat16 r[8];
    r[0] = __float2bfloat16(a.x); r[1] = __float2bfloat16(a.y);
    r[2] = __float2bfloat16(a.z); r[3] = __float2bfloat16(a.w);
    r[4] = __float2bfloat16(b.x); r[5] = __float2bfloat16(b.y);
    r[6] = __float2bfloat16(b.z); r[7] = __float2bfloat16(b.w);
    *(uint4*)(out + (size_t)i * 8) = *(const uint4*)r;
}

// ---------------------------------------------------------------------------
// MFMA GEMM: Y(M,NDIM) = A(M,256) @ W(NDIM,256)^T + bias (unchanged, round 1).
// ---------------------------------------------------------------------------
template<int NDIM, bool OUT_BF16>
__global__ __launch_bounds__(256) void gemm_mfma(
    const __hip_bfloat16* __restrict__ A,
    const __hip_bfloat16* __restrict__ W,
    const float* __restrict__ bias,
    void* __restrict__ Yv)
{
    const int K = 256;
    __shared__ short As[128 * 64];
    __shared__ short Bs[128 * 64];
    const int t = threadIdx.x;
    const int lane = t & 63, w = t >> 6;
    const int wr = w >> 1, wc = w & 1;
    const int q = lane >> 4, l15 = lane & 15;
    const int m0 = blockIdx.y * 128, n0 = blockIdx.x * 128;

    const int srow = t >> 3, skb = t & 7;
    const int gkb = skb ^ (srow & 7);
    const __hip_bfloat16* Ag = A + (size_t)(m0 + srow) * K + gkb * 8;
    const __hip_bfloat16* Wg = W + (size_t)(n0 + srow) * K + gkb * 8;

    floatx4 acc[4][4] = {};
    const int swz = l15 & 7;

    for (int k0 = 0; k0 < K; k0 += 64) {
        __syncthreads();
        #pragma unroll
        for (int i = 0; i < 4; i++) {
            gld_lds16(Ag + (size_t)(i * 32) * K + k0, &As[i * 2048 + w * 512]);
            gld_lds16(Wg + (size_t)(i * 32) * K + k0, &Bs[i * 2048 + w * 512]);
        }
        __syncthreads();
        #pragma unroll
        for (int kk = 0; kk < 2; kk++) {
            const int kbs = ((kk << 2) + q) ^ swz;
            short8 af[4], bf[4];
            #pragma unroll
            for (int i = 0; i < 4; i++) {
                af[i] = *(const short8*)&As[(wr * 64 + i * 16 + l15) * 64 + kbs * 8];
                bf[i] = *(const short8*)&Bs[(wc * 64 + i * 16 + l15) * 64 + kbs * 8];
            }
            #pragma unroll
            for (int i = 0; i < 4; i++)
                #pragma unroll
                for (int j = 0; j < 4; j++)
                    acc[i][j] = __builtin_amdgcn_mfma_f32_16x16x32_bf16(
                        af[i], bf[j], acc[i][j], 0, 0, 0);
        }
    }

    #pragma unroll
    for (int j = 0; j < 4; j++) {
        const int n = n0 + wc * 64 + j * 16 + l15;
        const float bv = bias[n];
        #pragma unroll
        for (int i = 0; i < 4; i++) {
            #pragma unroll
            for (int r = 0; r < 4; r++) {
                const int m = m0 + wr * 64 + i * 16 + q * 4 + r;
                const float val = acc[i][j][r] + bv;
                if (OUT_BF16)
                    ((__hip_bfloat16*)Yv)[(size_t)m * NDIM + n] = __float2bfloat16(val);
                else
                    ((float*)Yv)[(size_t)m * NDIM + n] = val;
            }
        }
    }
}

// ---------------------------------------------------------------------------
// MFMA attention: one block (4 waves) per (b,h).
// LDS (28.9 KB -> 5 blocks/CU):
//   [0     ) Q bf16 64x40 (rows 0..48 staged)  |  later overlaid by P bf16 64x72
//   [5120  ) K bf16 64x40
//   [10240 ) Vt bf16 32x72 (V transposed, cols>=49 zeroed)
//   [14848 ) S fp32 49x68
//   [28176 ) bias table slice 169 fp32
// Phases: zero/tab -> stage -> S=QK^T (MFMA, wave w = m-tile w) -> 3-way
// softmax (wave per row; P=p0+p1-p2 -> bf16 LDS, A-layout) -> O=PV (MFMA).
// ---------------------------------------------------------------------------
__global__ __launch_bounds__(256) void attn_kernel(
    const __hip_bfloat16* __restrict__ Y,   // (B*49, 768) bf16
    const float* __restrict__ wmask,        // (64, 49, 49)
    const float* __restrict__ fg,           // (B, 49, 49)
    const float* __restrict__ bg,           // (B, 49, 49)
    const float* __restrict__ table,        // (169, 8)
    __hip_bfloat16* __restrict__ O)         // (B*49, 256) bf16 -> ws
{
    __shared__ char lds[28864];
    __hip_bfloat16* sQ  = (__hip_bfloat16*)(lds);            // 64 x 40
    __hip_bfloat16* sK  = (__hip_bfloat16*)(lds + 5120);     // 64 x 40
    __hip_bfloat16* sP  = (__hip_bfloat16*)(lds);            // 64 x 72 (overlay)
    __hip_bfloat16* sVt = (__hip_bfloat16*)(lds + 10240);    // 32 x 72
    float*          sS  = (float*)(lds + 14848);             // 49 x 68
    float*          stab = (float*)(lds + 28176);            // 169

    const int blk = blockIdx.x;
    const int b = blk >> 3, h = blk & 7;
    const int t = threadIdx.x;
    const int w = t >> 6, lane = t & 63;
    const int quad = lane >> 4, l15 = lane & 15;
    const float scale = 0.17677669529663687f;  // hd^-0.5

    // phase 0: zero Vt (pads cols 49..71), load per-head bias table
    for (int i = t; i < 1152; i += 256) ((unsigned int*)sVt)[i] = 0u;
    for (int i = t; i < 169; i += 256) stab[i] = table[i * 8 + h];
    __syncthreads();

    // phase 1: stage Q, K row-major (stride 40); V transposed (stride 72)
    const __hip_bfloat16* Yb = Y + (size_t)b * NTOK * QKV_N + h * HDIM;
    if (t < 196) {
        const int n = t >> 2, c = t & 3;  // row, 8-elem chunk
        uint4 qv = *(const uint4*)(Yb + (size_t)n * QKV_N + c * 8);
        uint4 kv = *(const uint4*)(Yb + (size_t)n * QKV_N + 256 + c * 8);
        uint4 vv = *(const uint4*)(Yb + (size_t)n * QKV_N + 512 + c * 8);
        *(uint4*)(sQ + n * 40 + c * 8) = qv;
        *(uint4*)(sK + n * 40 + c * 8) = kv;
        const __hip_bfloat16* vp = (const __hip_bfloat16*)&vv;
        #pragma unroll
        for (int j = 0; j < 8; j++)
            sVt[(c * 8 + j) * 72 + n] = vp[j];
    }
    __syncthreads();

    // phase 2: S = Q @ K^T. Wave w owns m-tile w (rows 16w..16w+15), 4 n-tiles.
    {
        short8 af = *(const short8*)(sQ + (w * 16 + l15) * 40 + quad * 8);
        #pragma unroll
        for (int nt = 0; nt < 4; nt++) {
            short8 bf = *(const short8*)(sK + (nt * 16 + l15) * 40 + quad * 8);
            floatx4 acc = {};
            acc = __builtin_amdgcn_mfma_f32_16x16x32_bf16(af, bf, acc, 0, 0, 0);
            #pragma unroll
            for (int r = 0; r < 4; r++) {
                const int row = w * 16 + quad * 4 + r;
                if (row < NTOK) sS[row * 68 + nt * 16 + l15] = acc[r];
            }
        }
    }
    __syncthreads();

    // phase 3: 3-way softmax + combine -> P (bf16, A-layout) overlaying Q/K.
    const float* wm  = wmask + (size_t)(b & 63) * (NTOK * NTOK);
    const float* fgb = fg + (size_t)b * (NTOK * NTOK);
    const float* bgb = bg + (size_t)b * (NTOK * NTOK);
    for (int i = w; i < NTOK; i += 4) {
        const bool ok = (lane < NTOK);
        float sb = -1e30f, fv = 0.f, bv = 0.f;
        if (ok) {
            const int qi = i / 7, qj = i - qi * 7;
            const int ki = lane / 7, kj = lane - ki * 7;
            sb = sS[i * 68 + lane] * scale
               + stab[(qi - ki + 6) * 13 + (qj - kj + 6)]
               + wm[i * NTOK + lane];
            fv = fgb[i * NTOK + lane];
            bv = bgb[i * NTOK + lane];
        }
        float x[3] = { sb, sb + fv, sb + bv };
        float pc = 0.f;
        #pragma unroll
        for (int v = 0; v < 3; v++) {
            float m = x[v];
            #pragma unroll
            for (int off = 32; off; off >>= 1) m = fmaxf(m, __shfl_xor(m, off));
            const float e = ok ? __expf(x[v] - m) : 0.f;
            float ssum = e;
            #pragma unroll
            for (int off = 32; off; off >>= 1) ssum += __shfl_xor(ssum, off);
            pc += (v == 2 ? -1.f : 1.f) * e / ssum;
        }
        sP[i * 72 + lane] = __float2bfloat16(pc);  // lanes>=49 write 0
    }
    __syncthreads();

    // phase 4: O = P @ V. Wave w -> m-tile w; 2 n-tiles (dims 0..15, 16..31);
    // K=64 via two chained MFMAs.
    floatx4 o0 = {}, o1 = {};
    {
        short8 a0 = *(const short8*)(sP + (w * 16 + l15) * 72 + quad * 8);
        short8 a1 = *(const short8*)(sP + (w * 16 + l15) * 72 + 32 + quad * 8);
        short8 b00 = *(const short8*)(sVt + l15 * 72 + quad * 8);
        short8 b01 = *(const short8*)(sVt + l15 * 72 + 32 + quad * 8);
        short8 b10 = *(const short8*)(sVt + (16 + l15) * 72 + quad * 8);
        short8 b11 = *(const short8*)(sVt + (16 + l15) * 72 + 32 + quad * 8);
        o0 = __builtin_amdgcn_mfma_f32_16x16x32_bf16(a0, b00, o0, 0, 0, 0);
        o0 = __builtin_amdgcn_mfma_f32_16x16x32_bf16(a1, b01, o0, 0, 0, 0);
        o1 = __builtin_amdgcn_mfma_f32_16x16x32_bf16(a0, b10, o1, 0, 0, 0);
        o1 = __builtin_amdgcn_mfma_f32_16x16x32_bf16(a1, b11, o1, 0, 0, 0);
    }
    __hip_bfloat16* Ob = O + (size_t)b * NTOK * CDIM + h * HDIM;
    #pragma unroll
    for (int r = 0; r < 4; r++) {
        const int m = w * 16 + quad * 4 + r;
        if (m < NTOK) {
            Ob[(size_t)m * CDIM + l15]      = __float2bfloat16(o0[r]);
            Ob[(size_t)m * CDIM + 16 + l15] = __float2bfloat16(o1[r]);
        }
    }
}

extern "C" void kernel_launch(void* const* d_in, const int* in_sizes, int n_in,
                              void* d_out, int out_size, void* d_ws, size_t ws_size,
                              hipStream_t stream) {
    const float* x      = (const float*)d_in[0];
    const float* mask   = (const float*)d_in[1];
    const float* fg     = (const float*)d_in[2];
    const float* bg     = (const float*)d_in[3];
    const float* qkv_w  = (const float*)d_in[4];
    const float* qkv_b  = (const float*)d_in[5];
    const float* proj_w = (const float*)d_in[6];
    const float* proj_b = (const float*)d_in[7];
    const float* table  = (const float*)d_in[8];
    float* out = (float*)d_out;

    char* ws = (char*)d_ws;
    __hip_bfloat16* xb  = (__hip_bfloat16*)(ws);                    //  51,380,224 B
    __hip_bfloat16* Ybf = (__hip_bfloat16*)(ws + 51380224);         // 154,140,672 B
    __hip_bfloat16* Obf = (__hip_bfloat16*)(ws + 205520896);        //  51,380,224 B
    __hip_bfloat16* qwb = (__hip_bfloat16*)(ws + 256901120);        //     393,216 B
    __hip_bfloat16* pwb = (__hip_bfloat16*)(ws + 257294336);        //     131,072 B

    dim3 blk(256);
    cast_kernel<<<dim3((MROWS * CDIM / 8 + 255) / 256), blk, 0, stream>>>(x, xb, MROWS * CDIM / 8);
    cast_kernel<<<dim3((QKV_N * CDIM / 8 + 255) / 256), blk, 0, stream>>>(qkv_w, qwb, QKV_N * CDIM / 8);
    cast_kernel<<<dim3((CDIM * CDIM / 8 + 255) / 256), blk, 0, stream>>>(proj_w, pwb, CDIM * CDIM / 8);

    gemm_mfma<QKV_N, true><<<dim3(QKV_N / 128, MROWS / 128), blk, 0, stream>>>(xb, qwb, qkv_b, Ybf);
    attn_kernel<<<dim3(B_TOT * NHEAD), blk, 0, stream>>>(Ybf, mask, fg, bg, table, Obf);
    gemm_mfma<CDIM, false><<<dim3(CDIM / 128, MROWS / 128), blk, 0, stream>>>(Obf, pwb, proj_b, out);
}

// Round 4
// 453.367 us; speedup vs baseline: 4.3023x; 1.4561x over previous
//
#include <hip/hip_runtime.h>
#include <hip/hip_bf16.h>
#include <math.h>

// WindowAttention on MI355X — round 3: in-register C-layout softmax.
// attn: 2 barriers (was 4), no fp32-S LDS round trip, masks prefetched to
// VGPRs before staging, 4-step quad-local shuffle reductions (was 6-step
// row-per-wave). GEMMs/casts unchanged from round 2.
// av(p)+av(p_fg)-av(p_bg) == (p+p_fg-p_bg)@v  => single PV matmul.

#define B_TOT   2048
#define NTOK    49
#define CDIM    256
#define NHEAD   8
#define HDIM    32
#define MROWS   (B_TOT * NTOK)   // 100352
#define QKV_N   (3 * CDIM)       // 768

typedef __attribute__((ext_vector_type(8))) short short8;   // 8 bf16 (4 VGPRs)
typedef __attribute__((ext_vector_type(4))) float floatx4;  // MFMA acc

typedef unsigned int u32_g __attribute__((address_space(1)));
typedef unsigned int u32_l __attribute__((address_space(3)));

__device__ __forceinline__ void gld_lds16(const void* g, void* l) {
    __builtin_amdgcn_global_load_lds((const u32_g*)g, (u32_l*)l, 16, 0, 0);
}

// ---------------------------------------------------------------------------
// cast fp32 -> bf16, 8 elems/thread.
// ---------------------------------------------------------------------------
__global__ __launch_bounds__(256) void cast_kernel(
    const float* __restrict__ in, __hip_bfloat16* __restrict__ out, int n8)
{
    const int i = blockIdx.x * 256 + threadIdx.x;
    if (i >= n8) return;
    const float4* p = (const float4*)in + (size_t)i * 2;
    float4 a = p[0], b = p[1];
    __hip_bfloat16 r[8];
    r[0] = __float2bfloat16(a.x); r[1] = __float2bfloat16(a.y);
    r[2] = __float2bfloat16(a.z); r[3] = __float2bfloat16(a.w);
    r[4] = __float2bfloat16(b.x); r[5] = __float2bfloat16(b.y);
    r[6] = __float2bfloat16(b.z); r[7] = __float2bfloat16(b.w);
    *(uint4*)(out + (size_t)i * 8) = *(const uint4*)r;
}

// ---------------------------------------------------------------------------
// MFMA GEMM: Y(M,NDIM) = A(M,256) @ W(NDIM,256)^T + bias (unchanged, round 1).
// ---------------------------------------------------------------------------
template<int NDIM, bool OUT_BF16>
__global__ __launch_bounds__(256) void gemm_mfma(
    const __hip_bfloat16* __restrict__ A,
    const __hip_bfloat16* __restrict__ W,
    const float* __restrict__ bias,
    void* __restrict__ Yv)
{
    const int K = 256;
    __shared__ short As[128 * 64];
    __shared__ short Bs[128 * 64];
    const int t = threadIdx.x;
    const int lane = t & 63, w = t >> 6;
    const int wr = w >> 1, wc = w & 1;
    const int q = lane >> 4, l15 = lane & 15;
    const int m0 = blockIdx.y * 128, n0 = blockIdx.x * 128;

    const int srow = t >> 3, skb = t & 7;
    const int gkb = skb ^ (srow & 7);
    const __hip_bfloat16* Ag = A + (size_t)(m0 + srow) * K + gkb * 8;
    const __hip_bfloat16* Wg = W + (size_t)(n0 + srow) * K + gkb * 8;

    floatx4 acc[4][4] = {};
    const int swz = l15 & 7;

    for (int k0 = 0; k0 < K; k0 += 64) {
        __syncthreads();
        #pragma unroll
        for (int i = 0; i < 4; i++) {
            gld_lds16(Ag + (size_t)(i * 32) * K + k0, &As[i * 2048 + w * 512]);
            gld_lds16(Wg + (size_t)(i * 32) * K + k0, &Bs[i * 2048 + w * 512]);
        }
        __syncthreads();
        #pragma unroll
        for (int kk = 0; kk < 2; kk++) {
            const int kbs = ((kk << 2) + q) ^ swz;
            short8 af[4], bf[4];
            #pragma unroll
            for (int i = 0; i < 4; i++) {
                af[i] = *(const short8*)&As[(wr * 64 + i * 16 + l15) * 64 + kbs * 8];
                bf[i] = *(const short8*)&Bs[(wc * 64 + i * 16 + l15) * 64 + kbs * 8];
            }
            #pragma unroll
            for (int i = 0; i < 4; i++)
                #pragma unroll
                for (int j = 0; j < 4; j++)
                    acc[i][j] = __builtin_amdgcn_mfma_f32_16x16x32_bf16(
                        af[i], bf[j], acc[i][j], 0, 0, 0);
        }
    }

    #pragma unroll
    for (int j = 0; j < 4; j++) {
        const int n = n0 + wc * 64 + j * 16 + l15;
        const float bv = bias[n];
        #pragma unroll
        for (int i = 0; i < 4; i++) {
            #pragma unroll
            for (int r = 0; r < 4; r++) {
                const int m = m0 + wr * 64 + i * 16 + q * 4 + r;
                const float val = acc[i][j][r] + bv;
                if (OUT_BF16)
                    ((__hip_bfloat16*)Yv)[(size_t)m * NDIM + n] = __float2bfloat16(val);
                else
                    ((float*)Yv)[(size_t)m * NDIM + n] = val;
            }
        }
    }
}

// ---------------------------------------------------------------------------
// MFMA attention, one block (4 waves) per (b,h). 2 barriers.
// LDS (24.7 KB): sQ 64x40 bf16 | sK 64x40 | sVt 32x72 (V^T, k-pad zeroed) |
//                sP 64x72 bf16 | stab 169 fp32.
// Phase A: prefetch wm/fg/bg -> 48 VGPRs; stage Q/K/Vt; stab; zero Vt pad.
// Phase B: S = QK^T (regs) -> in-register 3-way softmax in C-layout -> sP.
// Phase C: O = P @ V -> global bf16.
// Garbage policy: rows>=49 flow as NaN, discarded at bounds-checked store;
// cols>=49 masked to -1e30 pre-reduction; Vt k in [49,64] zeroed (0*NaN trap).
// ---------------------------------------------------------------------------
__global__ __launch_bounds__(256, 4) void attn_kernel(
    const __hip_bfloat16* __restrict__ Y,   // (B*49, 768) bf16
    const float* __restrict__ wmask,        // (64, 49, 49)
    const float* __restrict__ fg,           // (B, 49, 49)
    const float* __restrict__ bg,           // (B, 49, 49)
    const float* __restrict__ table,        // (169, 8)
    __hip_bfloat16* __restrict__ O)         // (B*49, 256) bf16 -> ws
{
    __shared__ __hip_bfloat16 sQ[64 * 40];
    __shared__ __hip_bfloat16 sK[64 * 40];
    __shared__ __hip_bfloat16 sVt[32 * 72];
    __shared__ __hip_bfloat16 sP[64 * 72];
    __shared__ float stab[169];

    const int blk = blockIdx.x;
    const int b = blk >> 3, h = blk & 7;
    const int t = threadIdx.x;
    const int w = t >> 6, lane = t & 63;
    const int quad = lane >> 4, l15 = lane & 15;
    const float scale = 0.17677669529663687f;  // hd^-0.5

    // ---- phase A ----
    // mask prefetch into registers (issued first; latency overlaps staging).
    const float* wm  = wmask + (size_t)(b & 63) * (NTOK * NTOK);
    const float* fgb = fg + (size_t)b * (NTOK * NTOK);
    const float* bgb = bg + (size_t)b * (NTOK * NTOK);
    float mwm[16], mfg[16], mbg[16];
    #pragma unroll
    for (int r = 0; r < 4; r++) {
        const int row = w * 16 + quad * 4 + r;
        #pragma unroll
        for (int nt = 0; nt < 4; nt++) {
            const int col = nt * 16 + l15;
            const int sidx = (row < NTOK && col < NTOK) ? row * NTOK + col : 0;
            mwm[r * 4 + nt] = wm[sidx];
            mfg[r * 4 + nt] = fgb[sidx];
            mbg[r * 4 + nt] = bgb[sidx];
        }
    }
    // per-head bias table slice
    if (t < 169) stab[t] = table[t * 8 + h];
    // stage Q, K row-major (stride 40); V transposed (stride 72)
    const __hip_bfloat16* Yb = Y + (size_t)b * NTOK * QKV_N + h * HDIM;
    if (t < 196) {
        const int n = t >> 2, c = t & 3;  // row, 8-elem chunk
        uint4 qv = *(const uint4*)(Yb + (size_t)n * QKV_N + c * 8);
        uint4 kv = *(const uint4*)(Yb + (size_t)n * QKV_N + 256 + c * 8);
        uint4 vv = *(const uint4*)(Yb + (size_t)n * QKV_N + 512 + c * 8);
        *(uint4*)(sQ + n * 40 + c * 8) = qv;
        *(uint4*)(sK + n * 40 + c * 8) = kv;
        const __hip_bfloat16* vp = (const __hip_bfloat16*)&vv;
        #pragma unroll
        for (int j = 0; j < 8; j++)
            sVt[(c * 8 + j) * 72 + n] = vp[j];
    }
    // zero Vt k-pad: cols 49..64 of 32 rows (512 elems; col 64 harmless).
    {
        const __hip_bfloat16 z = __float2bfloat16(0.f);
        #pragma unroll
        for (int it = 0; it < 2; it++) {
            const int idx = t + it * 256;  // 0..511
            const int d = idx >> 4, c = 49 + (idx & 15);
            sVt[d * 72 + c] = z;
        }
    }
    __syncthreads();

    // ---- phase B: S = Q K^T in registers ----
    floatx4 acc[4];
    {
        short8 af = *(const short8*)(sQ + (w * 16 + l15) * 40 + quad * 8);
        #pragma unroll
        for (int nt = 0; nt < 4; nt++) {
            short8 bf = *(const short8*)(sK + (nt * 16 + l15) * 40 + quad * 8);
            floatx4 z = {};
            acc[nt] = __builtin_amdgcn_mfma_f32_16x16x32_bf16(af, bf, z, 0, 0, 0);
        }
    }

    // base scores: S*scale + rel-pos bias + window mask; invalid cols -> -1e30
    float xbase[16];
    #pragma unroll
    for (int r = 0; r < 4; r++) {
        const int row = w * 16 + quad * 4 + r;
        const int rc = min(row, 48);
        const int qi = (rc * 146) >> 10, qj = rc - qi * 7;  // rc/7, rc%7
        #pragma unroll
        for (int nt = 0; nt < 4; nt++) {
            const int col = nt * 16 + l15;
            const int cc = min(col, 48);
            const int ki = (cc * 146) >> 10, kj = cc - ki * 7;
            const float tb = stab[(qi - ki + 6) * 13 + (qj - kj + 6)];
            const float s = acc[nt][r] * scale + tb + mwm[r * 4 + nt];
            xbase[r * 4 + nt] = (col < NTOK) ? s : -1e30f;
        }
    }

    // 3-way softmax in C-layout; quad-local 4-step shuffle reductions.
    float pc[16];
    #pragma unroll
    for (int i = 0; i < 16; i++) pc[i] = 0.f;
    #pragma unroll
    for (int v = 0; v < 3; v++) {   // order: fg, bg, base (frees mfg/mbg early)
        float xv[16];
        #pragma unroll
        for (int i = 0; i < 16; i++)
            xv[i] = (v == 0) ? xbase[i] + mfg[i]
                  : (v == 1) ? xbase[i] + mbg[i]
                  : xbase[i];
        float mr[4];
        #pragma unroll
        for (int r = 0; r < 4; r++)
            mr[r] = fmaxf(fmaxf(xv[r * 4], xv[r * 4 + 1]),
                          fmaxf(xv[r * 4 + 2], xv[r * 4 + 3]));
        #pragma unroll
        for (int st = 1; st < 16; st <<= 1)
            #pragma unroll
            for (int r = 0; r < 4; r++)
                mr[r] = fmaxf(mr[r], __shfl_xor(mr[r], st));
        #pragma unroll
        for (int i = 0; i < 16; i++)
            xv[i] = __expf(xv[i] - mr[i >> 2]);
        float sr[4];
        #pragma unroll
        for (int r = 0; r < 4; r++)
            sr[r] = (xv[r * 4] + xv[r * 4 + 1]) + (xv[r * 4 + 2] + xv[r * 4 + 3]);
        #pragma unroll
        for (int st = 1; st < 16; st <<= 1)
            #pragma unroll
            for (int r = 0; r < 4; r++)
                sr[r] += __shfl_xor(sr[r], st);
        #pragma unroll
        for (int r = 0; r < 4; r++)
            sr[r] = __builtin_amdgcn_rcpf(sr[r]);
        const float sgn = (v == 1) ? -1.f : 1.f;
        #pragma unroll
        for (int i = 0; i < 16; i++)
            pc[i] += sgn * xv[i] * sr[i >> 2];
    }

    // P -> LDS (bf16, row-major stride 72 = A-operand layout for PV).
    #pragma unroll
    for (int r = 0; r < 4; r++) {
        const int row = w * 16 + quad * 4 + r;
        #pragma unroll
        for (int nt = 0; nt < 4; nt++)
            sP[row * 72 + nt * 16 + l15] = __float2bfloat16(pc[r * 4 + nt]);
    }
    __syncthreads();

    // ---- phase C: O = P @ V ----
    floatx4 o0 = {}, o1 = {};
    {
        short8 a0  = *(const short8*)(sP + (w * 16 + l15) * 72 + quad * 8);
        short8 a1  = *(const short8*)(sP + (w * 16 + l15) * 72 + 32 + quad * 8);
        short8 b00 = *(const short8*)(sVt + l15 * 72 + quad * 8);
        short8 b01 = *(const short8*)(sVt + l15 * 72 + 32 + quad * 8);
        short8 b10 = *(const short8*)(sVt + (16 + l15) * 72 + quad * 8);
        short8 b11 = *(const short8*)(sVt + (16 + l15) * 72 + 32 + quad * 8);
        o0 = __builtin_amdgcn_mfma_f32_16x16x32_bf16(a0, b00, o0, 0, 0, 0);
        o0 = __builtin_amdgcn_mfma_f32_16x16x32_bf16(a1, b01, o0, 0, 0, 0);
        o1 = __builtin_amdgcn_mfma_f32_16x16x32_bf16(a0, b10, o1, 0, 0, 0);
        o1 = __builtin_amdgcn_mfma_f32_16x16x32_bf16(a1, b11, o1, 0, 0, 0);
    }
    __hip_bfloat16* Ob = O + (size_t)b * NTOK * CDIM + h * HDIM;
    #pragma unroll
    for (int r = 0; r < 4; r++) {
        const int m = w * 16 + quad * 4 + r;
        if (m < NTOK) {
            Ob[(size_t)m * CDIM + l15]      = __float2bfloat16(o0[r]);
            Ob[(size_t)m * CDIM + 16 + l15] = __float2bfloat16(o1[r]);
        }
    }
}

extern "C" void kernel_launch(void* const* d_in, const int* in_sizes, int n_in,
                              void* d_out, int out_size, void* d_ws, size_t ws_size,
                              hipStream_t stream) {
    const float* x      = (const float*)d_in[0];
    const float* mask   = (const float*)d_in[1];
    const float* fg     = (const float*)d_in[2];
    const float* bg     = (const float*)d_in[3];
    const float* qkv_w  = (const float*)d_in[4];
    const float* qkv_b  = (const float*)d_in[5];
    const float* proj_w = (const float*)d_in[6];
    const float* proj_b = (const float*)d_in[7];
    const float* table  = (const float*)d_in[8];
    float* out = (float*)d_out;

    char* ws = (char*)d_ws;
    __hip_bfloat16* xb  = (__hip_bfloat16*)(ws);                    //  51,380,224 B
    __hip_bfloat16* Ybf = (__hip_bfloat16*)(ws + 51380224);         // 154,140,672 B
    __hip_bfloat16* Obf = (__hip_bfloat16*)(ws + 205520896);        //  51,380,224 B
    __hip_bfloat16* qwb = (__hip_bfloat16*)(ws + 256901120);        //     393,216 B
    __hip_bfloat16* pwb = (__hip_bfloat16*)(ws + 257294336);        //     131,072 B

    dim3 blk(256);
    cast_kernel<<<dim3((MROWS * CDIM / 8 + 255) / 256), blk, 0, stream>>>(x, xb, MROWS * CDIM / 8);
    cast_kernel<<<dim3((QKV_N * CDIM / 8 + 255) / 256), blk, 0, stream>>>(qkv_w, qwb, QKV_N * CDIM / 8);
    cast_kernel<<<dim3((CDIM * CDIM / 8 + 255) / 256), blk, 0, stream>>>(proj_w, pwb, CDIM * CDIM / 8);

    gemm_mfma<QKV_N, true><<<dim3(QKV_N / 128, MROWS / 128), blk, 0, stream>>>(xb, qwb, qkv_b, Ybf);
    attn_kernel<<<dim3(B_TOT * NHEAD), blk, 0, stream>>>(Ybf, mask, fg, bg, table, Obf);
    gemm_mfma<CDIM, false><<<dim3(CDIM / 128, MROWS / 128), blk, 0, stream>>>(Obf, pwb, proj_b, out);
}